// Round 6
// baseline (218.315 us; speedup 1.0000x reference)
//
#include <hip/hip_runtime.h>
#include <hip/hip_bf16.h>

#define B_SZ 2
#define SEQ 2048
#define DMODEL 128
#define DINNER 1024
#define NHEADS 8
#define HEADDIM 128
#define DSTATE 128
#define CONVDIM 1280
#define NPROJ 2304       /* z (1024) + xBC (1280) — GEMM part of in_proj */
#define NTOK (B_SZ*SEQ)  /* 4096 */
#define CHUNK 64
#define NCHUNK (SEQ/CHUNK) /* 32 */
#define LDT 72           /* padded t-stride for LDS tiles (16B-aligned rows) */
#define LDN 136          /* padded n-stride for natural-layout B/C tiles */

using bf16_t = __hip_bfloat16;
using short8 = __attribute__((ext_vector_type(8))) short;
using short4v= __attribute__((ext_vector_type(4))) short;
using f32x4  = __attribute__((ext_vector_type(4))) float;

__device__ __forceinline__ float silu_f(float x) { return x / (1.f + expf(-x)); }
__device__ __forceinline__ float bf2f(short s) {
    unsigned u = ((unsigned)(unsigned short)s) << 16;
    return __uint_as_float(u);
}
__device__ __forceinline__ short f2bf_s(float f) {
    bf16_t h = __float2bfloat16(f);
    return *(short*)&h;
}

// ---------------- fused cast of 3 weight tensors fp32 -> bf16 ----------------
__global__ __launch_bounds__(256) void cast3(const float* __restrict__ a, int na,
                                             const float* __restrict__ b, int nb,
                                             const float* __restrict__ c, int nc,
                                             bf16_t* __restrict__ oa,
                                             bf16_t* __restrict__ ob,
                                             bf16_t* __restrict__ oc) {
    int i = blockIdx.x * 256 + threadIdx.x;
    if (i < na) oa[i] = __float2bfloat16(a[i]);
    else if (i < na + nb) ob[i - na] = __float2bfloat16(b[i - na]);
    else if (i < na + nb + nc) oc[i - na - nb] = __float2bfloat16(c[i - na - nb]);
}

// ---------------- LayerNorm (128 wide), fp32+bf16 out (LN1) ----------------
__global__ __launch_bounds__(128) void ln_ker(const float* __restrict__ x,
                                              const float* __restrict__ w,
                                              const float* __restrict__ b,
                                              float* __restrict__ out_f,
                                              bf16_t* __restrict__ out_b) {
    int m = blockIdx.x, t = threadIdx.x;
    __shared__ float red[128];
    float v = x[(size_t)m*DMODEL + t];
    red[t] = v; __syncthreads();
    for (int s = 64; s > 0; s >>= 1) { if (t < s) red[t] += red[t+s]; __syncthreads(); }
    float mean = red[0] * (1.f/128.f);
    __syncthreads();
    float xc = v - mean;
    red[t] = xc * xc; __syncthreads();
    for (int s = 64; s > 0; s >>= 1) { if (t < s) red[t] += red[t+s]; __syncthreads(); }
    float var = red[0] * (1.f/128.f);
    float o = xc * rsqrtf(var + 1e-5f) * w[t] + b[t];
    out_f[(size_t)m*DMODEL + t] = o;
    out_b[(size_t)m*DMODEL + t] = __float2bfloat16(o);
}

// ---------------- in_proj MFMA GEMM: C[M,N](bf16) = A[M,K] @ W[N,K]^T ----------------
__global__ __launch_bounds__(256) void gemm_bf(const bf16_t* __restrict__ A,
                                               const bf16_t* __restrict__ W,
                                               bf16_t* __restrict__ C,
                                               int M, int N, int K) {
    int tid = threadIdx.x;
    int wave = tid >> 6, lane = tid & 63;
    int m0 = blockIdx.x * 64 + wave * 16;
    int n0 = blockIdx.y * 64;
    int lr = lane & 15, quad = lane >> 4;
    f32x4 acc[4];
#pragma unroll
    for (int j = 0; j < 4; j++) acc[j] = (f32x4){0.f, 0.f, 0.f, 0.f};
    for (int k0 = 0; k0 < K; k0 += 32) {
        short8 a = *(const short8*)(A + (size_t)(m0 + lr)*K + k0 + quad*8);
#pragma unroll
        for (int j = 0; j < 4; j++) {
            short8 b = *(const short8*)(W + (size_t)(n0 + j*16 + lr)*K + k0 + quad*8);
            acc[j] = __builtin_amdgcn_mfma_f32_16x16x32_bf16(a, b, acc[j], 0, 0, 0);
        }
    }
#pragma unroll
    for (int j = 0; j < 4; j++)
#pragma unroll
        for (int r = 0; r < 4; r++) {
            int row = m0 + quad*4 + r;
            int col = n0 + j*16 + lr;
            C[(size_t)row*N + col] = __float2bfloat16(acc[j][r]);
        }
}

// ---------------- dt head: fp32 dot + softplus; store dt and log(dA)=dt*A ----------------
__global__ __launch_bounds__(256) void dt_ker(const float* __restrict__ h,
                                              const float* __restrict__ w_in,
                                              const float* __restrict__ dt_bias,
                                              const float* __restrict__ A_log,
                                              float* __restrict__ dt,
                                              float* __restrict__ ldA) {
    int idx = blockIdx.x * 256 + threadIdx.x;  // NTOK*NHEADS = 32768
    if (idx >= NTOK * NHEADS) return;
    int m = idx >> 3, hd = idx & 7;
    const float* hr = h + (size_t)m * DMODEL;
    const float* wr = w_in + (size_t)(NPROJ + hd) * DMODEL;
    float s = 0.f;
#pragma unroll 8
    for (int k = 0; k < DMODEL; k++) s += hr[k] * wr[k];
    s += dt_bias[hd];
    float dtv = (s > 20.f) ? s : log1pf(expf(s));
    float Av = -expf(A_log[hd]);
    dt[idx] = dtv;
    ldA[idx] = dtv * Av;
}

// ---- conv helper: depthwise causal conv (k=4) + bias for 4 consecutive channels ----
__device__ __forceinline__ void conv4(const bf16_t* __restrict__ zxb,
                                      const float* __restrict__ conv_w,
                                      const float* __restrict__ conv_b,
                                      int b, int l, int ch, float acc[4]) {
    f32x4 wv[4];
#pragma unroll
    for (int j = 0; j < 4; j++) {
        acc[j] = conv_b[ch + j];
        wv[j] = *(const f32x4*)(conv_w + (ch + j)*4);
    }
    int zcol = DINNER + ch;
#pragma unroll
    for (int k = 0; k < 4; k++) {
        int ll = l - 3 + k;
        if (ll >= 0) {
            short4v v = *(const short4v*)(zxb + (size_t)(b*SEQ + ll)*NPROJ + zcol);
#pragma unroll
            for (int j = 0; j < 4; j++) acc[j] += bf2f(v[j]) * wv[j][k];
        }
    }
}

// ---------------- scan phase A (conv inline): S_local = (X*w)^T @ B ----------------
__global__ __launch_bounds__(256) void scanA_conv(const bf16_t* __restrict__ zxb,
                                                  const float* __restrict__ conv_w,
                                                  const float* __restrict__ conv_b,
                                                  const float* __restrict__ dt,
                                                  const float* __restrict__ ldA,
                                                  bf16_t* __restrict__ Sloc,
                                                  float* __restrict__ Pbuf) {
    int bid = blockIdx.x;
    int c = bid & 31, hd = (bid >> 5) & 7, b = bid >> 8;
    int t = threadIdx.x, wave = t >> 6, lane = t & 63;
    int lr = lane & 15, quad = lane >> 4;
    __shared__ bf16_t XT[128*LDT];   // [p][t], pre-scaled by w_t
    __shared__ bf16_t BT[128*LDT];   // [n][t]
    __shared__ float ws[CHUNK];
    int m0tok = b*SEQ + c*CHUNK;
    int l0 = c*CHUNK;
    if (t < 64) {
        float L = ldA[(m0tok + t)*NHEADS + hd];
#pragma unroll
        for (int d = 1; d < 64; d <<= 1) {
            float u = __shfl_up(L, d, 64);
            if (lane >= d) L += u;
        }
        float Ltot = __shfl(L, 63, 64);
        ws[t] = expf(Ltot - L) * dt[(m0tok + t)*NHEADS + hd];
        if (t == 63) Pbuf[bid] = expf(Ltot);
    }
    __syncthreads();
#pragma unroll 2
    for (int i = 0; i < 16; i++) {
        int u = i*256 + t;
        int tt = u & 63;
        int cg2 = u >> 6;                   // 0..63: 0-31 X, 32-63 B
        bool isX = cg2 < 32;
        int ch = isX ? hd*HEADDIM + cg2*4 : DINNER + (cg2 - 32)*4;
        float acc[4];
        conv4(zxb, conv_w, conv_b, b, l0 + tt, ch, acc);
        if (isX) {
            float w_t = ws[tt];
#pragma unroll
            for (int j = 0; j < 4; j++)
                XT[(cg2*4 + j)*LDT + tt] = __float2bfloat16(silu_f(acc[j]) * w_t);
        } else {
#pragma unroll
            for (int j = 0; j < 4; j++)
                BT[((cg2-32)*4 + j)*LDT + tt] = __float2bfloat16(silu_f(acc[j]));
        }
    }
    __syncthreads();
    int m0w = wave * 32;
    f32x4 acc[2][8];
#pragma unroll
    for (int mi = 0; mi < 2; mi++)
#pragma unroll
        for (int ni = 0; ni < 8; ni++) acc[mi][ni] = (f32x4){0.f,0.f,0.f,0.f};
#pragma unroll
    for (int k0 = 0; k0 < 64; k0 += 32) {
        short8 a[2];
#pragma unroll
        for (int mi = 0; mi < 2; mi++)
            a[mi] = *(const short8*)&XT[(m0w + mi*16 + lr)*LDT + k0 + quad*8];
#pragma unroll
        for (int ni = 0; ni < 8; ni++) {
            short8 bb = *(const short8*)&BT[(ni*16 + lr)*LDT + k0 + quad*8];
#pragma unroll
            for (int mi = 0; mi < 2; mi++)
                acc[mi][ni] = __builtin_amdgcn_mfma_f32_16x16x32_bf16(a[mi], bb, acc[mi][ni], 0, 0, 0);
        }
    }
    bf16_t* outp = Sloc + (size_t)bid * 16384;
#pragma unroll
    for (int mi = 0; mi < 2; mi++)
#pragma unroll
        for (int ni = 0; ni < 8; ni++)
#pragma unroll
            for (int r = 0; r < 4; r++) {
                int p = m0w + mi*16 + quad*4 + r;
                int n = ni*16 + lr;
                outp[p*128 + n] = __float2bfloat16(acc[mi][ni][r]);
            }
}

// ---------------- scan phase B: inter-chunk recurrence, out-of-place, 512-way ----------------
__global__ __launch_bounds__(256) void scanB(const bf16_t* __restrict__ Sloc,
                                             bf16_t* __restrict__ Sini,
                                             const float* __restrict__ Pbuf) {
    int bid = blockIdx.x;                   // 512 = 16 bh * 32 slices
    int bh = bid >> 5, slice = bid & 31;
    int t = threadIdx.x;
    int off = slice*512 + t*2;
    size_t base = (size_t)bh * NCHUNK * 16384;
    float run0 = 0.f, run1 = 0.f;
    for (int cc = 0; cc < NCHUNK; cc++) {
        unsigned raw = *(const unsigned*)(Sloc + base + (size_t)cc*16384 + off);
        float P = Pbuf[bh*NCHUNK + cc];
        unsigned o0 = (unsigned)(unsigned short)f2bf_s(run0);
        unsigned o1 = (unsigned)(unsigned short)f2bf_s(run1);
        *(unsigned*)(Sini + base + (size_t)cc*16384 + off) = o0 | (o1 << 16);
        run0 = run0*P + bf2f((short)(raw & 0xffff));
        run1 = run1*P + bf2f((short)(raw >> 16));
    }
}

// ---------------- scan phase C (conv inline): Y = diag(e^L) C @ Sini^T + M @ X + D*x ----------------
__global__ __launch_bounds__(256, 2) void scanC_conv(const bf16_t* __restrict__ zxb,
                                                     const float* __restrict__ conv_w,
                                                     const float* __restrict__ conv_b,
                                                     const float* __restrict__ dt,
                                                     const float* __restrict__ ldA,
                                                     const bf16_t* __restrict__ Sini,
                                                     const float* __restrict__ Dskip,
                                                     float* __restrict__ ybuf) {
    int bid = blockIdx.x;
    int c = bid & 31, hd = (bid >> 5) & 7, b = bid >> 8;
    int t = threadIdx.x, wave = t >> 6, lane = t & 63;
    int lr = lane & 15, quad = lane >> 4;
    __shared__ bf16_t XT[128*LDT];   // [p][t] raw
    __shared__ bf16_t Mlds[64*LDT];  // [t][s]
    __shared__ bf16_t Ct[64*LDN];    // [t][n]
    __shared__ bf16_t Bt[64*LDN];    // [t][n]
    __shared__ float Ls[CHUNK], dts[CHUNK];
    int m0tok = b*SEQ + c*CHUNK;
    int l0 = c*CHUNK;
    if (t < 64) {
        float L = ldA[(m0tok + t)*NHEADS + hd];
#pragma unroll
        for (int d = 1; d < 64; d <<= 1) {
            float u = __shfl_up(L, d, 64);
            if (lane >= d) L += u;
        }
        Ls[t] = L;
        dts[t] = dt[(m0tok + t)*NHEADS + hd];
    }
    // staging with inline conv: X (transposed), B, C (natural [t][n])
#pragma unroll 2
    for (int i = 0; i < 24; i++) {
        int u = i*256 + t;
        int tt = u & 63;
        int cg2 = u >> 6;                   // 0..95: 0-31 X, 32-63 B, 64-95 C
        int ch;
        if (cg2 < 32)      ch = hd*HEADDIM + cg2*4;
        else if (cg2 < 64) ch = DINNER + (cg2 - 32)*4;
        else               ch = DINNER + DSTATE + (cg2 - 64)*4;
        float acc[4];
        conv4(zxb, conv_w, conv_b, b, l0 + tt, ch, acc);
        if (cg2 < 32) {
#pragma unroll
            for (int j = 0; j < 4; j++)
                XT[(cg2*4 + j)*LDT + tt] = __float2bfloat16(silu_f(acc[j]));
        } else {
            short4v pk;
#pragma unroll
            for (int j = 0; j < 4; j++) pk[j] = f2bf_s(silu_f(acc[j]));
            if (cg2 < 64) *(short4v*)&Bt[tt*LDN + (cg2-32)*4] = pk;
            else          *(short4v*)&Ct[tt*LDN + (cg2-64)*4] = pk;
        }
    }
    __syncthreads();
    // --- G = C @ B^T for t-rows [wave*16, wave*16+16) ---
    f32x4 g[4];
#pragma unroll
    for (int si = 0; si < 4; si++) g[si] = (f32x4){0.f,0.f,0.f,0.f};
#pragma unroll
    for (int k0 = 0; k0 < 128; k0 += 32) {
        short8 a = *(const short8*)&Ct[(wave*16 + lr)*LDN + k0 + quad*8];
#pragma unroll
        for (int si = 0; si < 4; si++) {
            short8 bb = *(const short8*)&Bt[(si*16 + lr)*LDN + k0 + quad*8];
            g[si] = __builtin_amdgcn_mfma_f32_16x16x32_bf16(a, bb, g[si], 0, 0, 0);
        }
    }
#pragma unroll
    for (int si = 0; si < 4; si++)
#pragma unroll
        for (int r = 0; r < 4; r++) {
            int tt = wave*16 + quad*4 + r;
            int ss = si*16 + lr;
            float v = (ss <= tt) ? g[si][r] * expf(Ls[tt] - Ls[ss]) * dts[ss] : 0.f;
            Mlds[tt*LDT + ss] = __float2bfloat16(v);
        }
    __syncthreads();
    // --- Y: wave handles p-cols [wave*32, wave*32+32) ---
    int p0 = wave * 32;
    f32x4 acc[4][2];
#pragma unroll
    for (int mi = 0; mi < 4; mi++)
#pragma unroll
        for (int ni = 0; ni < 2; ni++) acc[mi][ni] = (f32x4){0.f,0.f,0.f,0.f};
    // Y_inter = C @ S_init^T  (K = n = 128)
    const bf16_t* Sb = Sini + (size_t)bid * 16384;
#pragma unroll
    for (int k0 = 0; k0 < 128; k0 += 32) {
        short8 aC[4];
#pragma unroll
        for (int mi = 0; mi < 4; mi++)
            aC[mi] = *(const short8*)&Ct[(mi*16 + lr)*LDN + k0 + quad*8];
#pragma unroll
        for (int ni = 0; ni < 2; ni++) {
            short8 bb = *(const short8*)(Sb + (size_t)(p0 + ni*16 + lr)*128 + k0 + quad*8);
#pragma unroll
            for (int mi = 0; mi < 4; mi++)
                acc[mi][ni] = __builtin_amdgcn_mfma_f32_16x16x32_bf16(aC[mi], bb, acc[mi][ni], 0, 0, 0);
        }
    }
    // scale rows by exp(L_t)
#pragma unroll
    for (int mi = 0; mi < 4; mi++) {
        float el[4];
#pragma unroll
        for (int r = 0; r < 4; r++) el[r] = expf(Ls[mi*16 + quad*4 + r]);
#pragma unroll
        for (int ni = 0; ni < 2; ni++)
#pragma unroll
            for (int r = 0; r < 4; r++) acc[mi][ni][r] *= el[r];
    }
    // Y_intra = M @ X  (K = s = 64)
#pragma unroll
    for (int k0 = 0; k0 < 64; k0 += 32) {
        short8 aM[4];
#pragma unroll
        for (int mi = 0; mi < 4; mi++)
            aM[mi] = *(const short8*)&Mlds[(mi*16 + lr)*LDT + k0 + quad*8];
#pragma unroll
        for (int ni = 0; ni < 2; ni++) {
            short8 bb = *(const short8*)&XT[(p0 + ni*16 + lr)*LDT + k0 + quad*8];
#pragma unroll
            for (int mi = 0; mi < 4; mi++)
                acc[mi][ni] = __builtin_amdgcn_mfma_f32_16x16x32_bf16(aM[mi], bb, acc[mi][ni], 0, 0, 0);
        }
    }
    float dsk = Dskip[hd];
#pragma unroll
    for (int mi = 0; mi < 4; mi++)
#pragma unroll
        for (int ni = 0; ni < 2; ni++)
#pragma unroll
            for (int r = 0; r < 4; r++) {
                int tt = mi*16 + quad*4 + r;
                int pp = p0 + ni*16 + lr;
                float xv = bf2f(*(const short*)&XT[pp*LDT + tt]);
                int m = m0tok + tt;
                ybuf[(size_t)m*DINNER + hd*HEADDIM + pp] = acc[mi][ni][r] + dsk*xv;
            }
}

// ---------------- fused gate(silu(z)) + RMSNorm + out_proj (16 tokens/block) ----------------
__global__ __launch_bounds__(256) void gate_out(const float* __restrict__ ybuf,
                                                const bf16_t* __restrict__ zxb,
                                                const float* __restrict__ gw,
                                                const bf16_t* __restrict__ Wb,
                                                float* __restrict__ mix) {
    int blk = blockIdx.x, t = threadIdx.x;
    int tok0 = blk * 16;
    int tt = t >> 4, cg = t & 15;
    int ch0 = cg * 64;
    __shared__ bf16_t A[16*1032];
    float vals[64];
    const float*  yr = ybuf + (size_t)(tok0 + tt)*DINNER + ch0;
    const bf16_t* zr = zxb  + (size_t)(tok0 + tt)*NPROJ  + ch0;
    float ss = 0.f;
#pragma unroll
    for (int i = 0; i < 64; i += 4) {
        f32x4 y = *(const f32x4*)(yr + i);
        short4v z = *(const short4v*)(zr + i);
#pragma unroll
        for (int r = 0; r < 4; r++) {
            float v = y[r] * silu_f(bf2f(z[r]));
            vals[i + r] = v; ss += v*v;
        }
    }
#pragma unroll
    for (int d = 1; d < 16; d <<= 1) ss += __shfl_xor(ss, d, 64);
    float rstd = rsqrtf(ss*(1.f/1024.f) + 1e-5f);
#pragma unroll
    for (int i = 0; i < 64; i += 4) {
        short4v pk;
#pragma unroll
        for (int r = 0; r < 4; r++) pk[r] = f2bf_s(vals[i+r]*rstd*gw[ch0+i+r]);
        *(short4v*)&A[tt*1032 + ch0 + i] = pk;
    }
    __syncthreads();
    int wave = t >> 6, lane = t & 63, lr = lane & 15, quad = lane >> 4;
    f32x4 acc[2];
    acc[0] = (f32x4){0.f,0.f,0.f,0.f}; acc[1] = (f32x4){0.f,0.f,0.f,0.f};
    for (int k0 = 0; k0 < 1024; k0 += 32) {
        short8 a = *(const short8*)&A[lr*1032 + k0 + quad*8];
#pragma unroll
        for (int j = 0; j < 2; j++) {
            int col = wave*32 + j*16 + lr;
            short8 bb = *(const short8*)(Wb + (size_t)col*DINNER + k0 + quad*8);
            acc[j] = __builtin_amdgcn_mfma_f32_16x16x32_bf16(a, bb, acc[j], 0, 0, 0);
        }
    }
#pragma unroll
    for (int j = 0; j < 2; j++)
#pragma unroll
        for (int r = 0; r < 4; r++) {
            int row = tok0 + quad*4 + r;
            int col = wave*32 + j*16 + lr;
            mix[(size_t)row*DMODEL + col] = acc[j][r];
        }
}

// ---------------- fused residual + LN2 + MLP (16 tokens/block) ----------------
__global__ __launch_bounds__(256) void ln_mlp(const float* __restrict__ mix,
                                              const float* __restrict__ resid,
                                              const float* __restrict__ w,
                                              const float* __restrict__ b,
                                              const bf16_t* __restrict__ Wm,
                                              const float* __restrict__ mb,
                                              float* __restrict__ out) {
    int blk = blockIdx.x, t = threadIdx.x;
    int tok0 = blk * 16;
    int tt = t >> 4, cg = t & 15;
    int ch0 = cg * 8;
    __shared__ bf16_t A[16*136];
    const float* xr = mix   + (size_t)(tok0 + tt)*DMODEL + ch0;
    const float* rr = resid + (size_t)(tok0 + tt)*DMODEL + ch0;
    float v[8];
    {
        f32x4 x0 = *(const f32x4*)xr, x1 = *(const f32x4*)(xr + 4);
        f32x4 r0 = *(const f32x4*)rr, r1 = *(const f32x4*)(rr + 4);
#pragma unroll
        for (int r = 0; r < 4; r++) { v[r] = x0[r] + r0[r]; v[4+r] = x1[r] + r1[r]; }
    }
    float s = 0.f, sq = 0.f;
#pragma unroll
    for (int i = 0; i < 8; i++) { s += v[i]; sq += v[i]*v[i]; }
#pragma unroll
    for (int d = 1; d < 16; d <<= 1) { s += __shfl_xor(s, d, 64); sq += __shfl_xor(sq, d, 64); }
    float mean = s * (1.f/128.f);
    float var  = sq * (1.f/128.f) - mean*mean;
    float rstd = rsqrtf(var + 1e-5f);
    {
        short4v p0, p1;
#pragma unroll
        for (int r = 0; r < 4; r++) {
            p0[r] = f2bf_s((v[r]   - mean)*rstd*w[ch0+r]   + b[ch0+r]);
            p1[r] = f2bf_s((v[4+r] - mean)*rstd*w[ch0+4+r] + b[ch0+4+r]);
        }
        *(short4v*)&A[tt*136 + ch0]     = p0;
        *(short4v*)&A[tt*136 + ch0 + 4] = p1;
    }
    __syncthreads();
    int wave = t >> 6, lane = t & 63, lr = lane & 15, quad = lane >> 4;
    f32x4 acc[2];
    acc[0] = (f32x4){0.f,0.f,0.f,0.f}; acc[1] = (f32x4){0.f,0.f,0.f,0.f};
#pragma unroll
    for (int k0 = 0; k0 < 128; k0 += 32) {
        short8 a = *(const short8*)&A[lr*136 + k0 + quad*8];
#pragma unroll
        for (int j = 0; j < 2; j++) {
            int col = wave*32 + j*16 + lr;
            short8 bb = *(const short8*)(Wm + (size_t)col*DMODEL + k0 + quad*8);
            acc[j] = __builtin_amdgcn_mfma_f32_16x16x32_bf16(a, bb, acc[j], 0, 0, 0);
        }
    }
#pragma unroll
    for (int j = 0; j < 2; j++)
#pragma unroll
        for (int r = 0; r < 4; r++) {
            int row = tok0 + quad*4 + r;
            int col = wave*32 + j*16 + lr;
            out[(size_t)row*DMODEL + col] = acc[j][r] + mb[col];
        }
}

extern "C" void kernel_launch(void* const* d_in, const int* in_sizes, int n_in,
                              void* d_out, int out_size, void* d_ws, size_t ws_size,
                              hipStream_t stream) {
    const float* hidden  = (const float*)d_in[0];
    const float* w_in    = (const float*)d_in[1];
    const float* conv_w  = (const float*)d_in[2];
    const float* conv_b  = (const float*)d_in[3];
    const float* dt_bias = (const float*)d_in[4];
    const float* A_log   = (const float*)d_in[5];
    const float* D_skip  = (const float*)d_in[6];
    const float* gnorm_w = (const float*)d_in[7];
    const float* w_out   = (const float*)d_in[8];
    const float* ln1_w   = (const float*)d_in[9];
    const float* ln1_b   = (const float*)d_in[10];
    const float* ln2_w   = (const float*)d_in[11];
    const float* ln2_b   = (const float*)d_in[12];
    const float* mlp_w   = (const float*)d_in[13];
    const float* mlp_b   = (const float*)d_in[14];
    float* out = (float*)d_out;

    char* ws = (char*)d_ws;
    size_t off = 0;
    auto alloc = [&](size_t bytes) -> void* {
        void* p = ws + off;
        off = (off + bytes + 255) & ~(size_t)255;
        return p;
    };
    float*  h      = (float*) alloc((size_t)NTOK*DMODEL*4);
    bf16_t* h_bf   = (bf16_t*)alloc((size_t)NTOK*DMODEL*2);
    bf16_t* w_in_bf= (bf16_t*)alloc((size_t)NPROJ*DMODEL*2);
    bf16_t* w_out_bf=(bf16_t*)alloc((size_t)DMODEL*DINNER*2);
    bf16_t* mlp_bf = (bf16_t*)alloc((size_t)DMODEL*DMODEL*2);
    bf16_t* zx_bf  = (bf16_t*)alloc((size_t)NTOK*NPROJ*2);
    float*  dtb    = (float*) alloc((size_t)NTOK*NHEADS*4);
    float*  ldAb   = (float*) alloc((size_t)NTOK*NHEADS*4);
    bf16_t* Sloc   = (bf16_t*)alloc((size_t)B_SZ*NHEADS*NCHUNK*16384*2);
    bf16_t* Sini   = (bf16_t*)alloc((size_t)B_SZ*NHEADS*NCHUNK*16384*2);
    float*  Pbuf   = (float*) alloc((size_t)B_SZ*NHEADS*NCHUNK*4);
    float*  ybuf   = (float*) alloc((size_t)NTOK*DINNER*4);
    float*  mix    = (float*) alloc((size_t)NTOK*DMODEL*4);
    (void)ws_size; (void)in_sizes; (void)n_in; (void)out_size;

    // fused weight casts
    {
        int na = NPROJ*DMODEL, nb = DMODEL*DINNER, nc = DMODEL*DMODEL;
        cast3<<<(na+nb+nc + 255)/256, 256, 0, stream>>>(w_in, na, w_out, nb, mlp_w, nc,
                                                        w_in_bf, w_out_bf, mlp_bf);
    }
    // LN1
    ln_ker<<<NTOK, 128, 0, stream>>>(hidden, ln1_w, ln1_b, h, h_bf);
    // in_proj (z + xBC columns), bf16 out
    gemm_bf<<<dim3(NTOK/64, NPROJ/64), 256, 0, stream>>>(h_bf, w_in_bf, zx_bf,
                                                         NTOK, NPROJ, DMODEL);
    // dt heads (fp32 path)
    dt_ker<<<(NTOK*NHEADS + 255)/256, 256, 0, stream>>>(h, w_in, dt_bias, A_log, dtb, ldAb);
    // chunked scan (SSD, MFMA), conv folded into staging; SSA dataflow Sloc -> Sini
    scanA_conv<<<B_SZ*NHEADS*NCHUNK, 256, 0, stream>>>(zx_bf, conv_w, conv_b, dtb, ldAb,
                                                       Sloc, Pbuf);
    scanB<<<B_SZ*NHEADS*NCHUNK, 256, 0, stream>>>(Sloc, Sini, Pbuf);
    scanC_conv<<<B_SZ*NHEADS*NCHUNK, 256, 0, stream>>>(zx_bf, conv_w, conv_b, dtb, ldAb,
                                                       Sini, D_skip, ybuf);
    // fused gate + RMSNorm + out_proj
    gate_out<<<NTOK/16, 256, 0, stream>>>(ybuf, zx_bf, gnorm_w, w_out_bf, mix);
    // fused residual + LN2 + MLP
    ln_mlp<<<NTOK/16, 256, 0, stream>>>(mix, hidden, ln2_w, ln2_b, mlp_bf, mlp_b, out);
}

// Round 9
// 184.358 us; speedup vs baseline: 1.1842x; 1.1842x over previous
//
#include <hip/hip_runtime.h>
#include <hip/hip_bf16.h>

#define B_SZ 2
#define SEQ 2048
#define DMODEL 128
#define DINNER 1024
#define NHEADS 8
#define HEADDIM 128
#define DSTATE 128
#define CONVDIM 1280
#define NPROJ 2304       /* z (1024) + xBC (1280) — GEMM part of in_proj */
#define NTOK (B_SZ*SEQ)  /* 4096 */
#define CHUNK 64
#define NCHUNK (SEQ/CHUNK) /* 32 */
#define LDT 72           /* padded t-stride for LDS tiles (16B-aligned rows) */

using bf16_t = __hip_bfloat16;
using short8 = __attribute__((ext_vector_type(8))) short;
using short4v= __attribute__((ext_vector_type(4))) short;
using f32x4  = __attribute__((ext_vector_type(4))) float;

__device__ __forceinline__ float silu_f(float x) { return x / (1.f + expf(-x)); }
__device__ __forceinline__ float bf2f(short s) {
    unsigned u = ((unsigned)(unsigned short)s) << 16;
    return __uint_as_float(u);
}
__device__ __forceinline__ short f2bf_s(float f) {
    bf16_t h = __float2bfloat16(f);
    return *(short*)&h;
}

// ---- fused: weight casts (blocks >= NTOK) + LN1 + dt/softplus head (blocks < NTOK) ----
__global__ __launch_bounds__(128) void head_fused(
        const float* __restrict__ hidden,
        const float* __restrict__ ln1_w, const float* __restrict__ ln1_b,
        const float* __restrict__ w_in,
        const float* __restrict__ dt_bias, const float* __restrict__ A_log,
        bf16_t* __restrict__ h_bf, float* __restrict__ dtb, float* __restrict__ ldAb,
        const float* __restrict__ wa, int na, const float* __restrict__ wb, int nb,
        const float* __restrict__ wc, int nc,
        bf16_t* __restrict__ oa, bf16_t* __restrict__ ob, bf16_t* __restrict__ oc) {
    int blk = blockIdx.x;
    if (blk >= NTOK) {
        int i = (blk - NTOK) * 128 + threadIdx.x;
        if (i < na) oa[i] = __float2bfloat16(wa[i]);
        else if (i < na + nb) ob[i - na] = __float2bfloat16(wb[i - na]);
        else if (i < na + nb + nc) oc[i - na - nb] = __float2bfloat16(wc[i - na - nb]);
        return;
    }
    int m = blk, t = threadIdx.x;
    __shared__ float red[128];
    __shared__ float sred[2][8];
    float v = hidden[(size_t)m*DMODEL + t];
    red[t] = v; __syncthreads();
    for (int s = 64; s > 0; s >>= 1) { if (t < s) red[t] += red[t+s]; __syncthreads(); }
    float mean = red[0] * (1.f/128.f);
    __syncthreads();
    float xc = v - mean;
    red[t] = xc * xc; __syncthreads();
    for (int s = 64; s > 0; s >>= 1) { if (t < s) red[t] += red[t+s]; __syncthreads(); }
    float var = red[0] * (1.f/128.f);
    float o = xc * rsqrtf(var + 1e-5f) * ln1_w[t] + ln1_b[t];
    h_bf[(size_t)m*DMODEL + t] = __float2bfloat16(o);
    int wave = t >> 6, lane = t & 63;
#pragma unroll
    for (int hd = 0; hd < NHEADS; hd++) {
        float p = o * w_in[(size_t)(NPROJ + hd)*DMODEL + t];
#pragma unroll
        for (int d = 1; d < 64; d <<= 1) p += __shfl_xor(p, d, 64);
        if (lane == 0) sred[wave][hd] = p;
    }
    __syncthreads();
    if (t < NHEADS) {
        float s = sred[0][t] + sred[1][t] + dt_bias[t];
        float dtv = (s > 20.f) ? s : log1pf(expf(s));
        float Av = -expf(A_log[t]);
        dtb[m*NHEADS + t] = dtv;
        ldAb[m*NHEADS + t] = dtv * Av;
    }
}

// ---------------- in_proj MFMA GEMM: C[M,N](bf16) = A[M,K] @ W[N,K]^T ----------------
__global__ __launch_bounds__(256) void gemm_bf(const bf16_t* __restrict__ A,
                                               const bf16_t* __restrict__ W,
                                               bf16_t* __restrict__ C,
                                               int M, int N, int K) {
    int tid = threadIdx.x;
    int wave = tid >> 6, lane = tid & 63;
    int m0 = blockIdx.x * 64 + wave * 16;
    int n0 = blockIdx.y * 64;
    int lr = lane & 15, quad = lane >> 4;
    f32x4 acc[4];
#pragma unroll
    for (int j = 0; j < 4; j++) acc[j] = (f32x4){0.f, 0.f, 0.f, 0.f};
    for (int k0 = 0; k0 < K; k0 += 32) {
        short8 a = *(const short8*)(A + (size_t)(m0 + lr)*K + k0 + quad*8);
#pragma unroll
        for (int j = 0; j < 4; j++) {
            short8 b = *(const short8*)(W + (size_t)(n0 + j*16 + lr)*K + k0 + quad*8);
            acc[j] = __builtin_amdgcn_mfma_f32_16x16x32_bf16(a, b, acc[j], 0, 0, 0);
        }
    }
#pragma unroll
    for (int j = 0; j < 4; j++)
#pragma unroll
        for (int r = 0; r < 4; r++) {
            int row = m0 + quad*4 + r;
            int col = n0 + j*16 + lr;
            C[(size_t)row*N + col] = __float2bfloat16(acc[j][r]);
        }
}

// ---------------- depthwise causal conv (k=4) + bias + silu; x4 vectorized ----------------
__global__ __launch_bounds__(256) void conv_silu(const bf16_t* __restrict__ zxb,
                                                 const float* __restrict__ conv_w,
                                                 const float* __restrict__ conv_b,
                                                 bf16_t* __restrict__ xBCb) {
    int idx = blockIdx.x * 256 + threadIdx.x;   // NTOK*CONVDIM/4
    if (idx >= NTOK * CONVDIM / 4) return;
    int c4 = (idx % (CONVDIM/4)) * 4;
    int m  = idx / (CONVDIM/4);
    int b = m >> 11, l = m & (SEQ - 1);
    float acc[4];
    f32x4 wv[4];
#pragma unroll
    for (int j = 0; j < 4; j++) {
        acc[j] = conv_b[c4 + j];
        wv[j] = *(const f32x4*)(conv_w + (c4 + j)*4);
    }
#pragma unroll
    for (int k = 0; k < 4; k++) {
        int ll = l - 3 + k;
        if (ll >= 0) {
            short4v v = *(const short4v*)(zxb + (size_t)(b*SEQ + ll)*NPROJ + DINNER + c4);
#pragma unroll
            for (int j = 0; j < 4; j++) acc[j] += bf2f(v[j]) * wv[j][k];
        }
    }
    short4v res;
#pragma unroll
    for (int j = 0; j < 4; j++) res[j] = f2bf_s(silu_f(acc[j]));
    *(short4v*)(xBCb + (size_t)m*CONVDIM + c4) = res;
}

// ---------------- scan phase A (MFMA): chunk-local states S_local = (X*w)^T @ B ----------------
__global__ __launch_bounds__(256) void scanA_mfma(const bf16_t* __restrict__ xBCb,
                                                  const float* __restrict__ dt,
                                                  const float* __restrict__ ldA,
                                                  bf16_t* __restrict__ Sloc,
                                                  float* __restrict__ Pbuf) {
    int bid = blockIdx.x;
    int c = bid & 31, hd = (bid >> 5) & 7, b = bid >> 8;
    int t = threadIdx.x, wave = t >> 6, lane = t & 63;
    int lr = lane & 15, quad = lane >> 4;
    __shared__ bf16_t XT[128*LDT];   // [p][t], pre-scaled by w_t
    __shared__ bf16_t BT[128*LDT];   // [n][t]
    __shared__ float ws[CHUNK];
    int m0tok = b*SEQ + c*CHUNK;
    if (t < 64) {
        float L = ldA[(m0tok + t)*NHEADS + hd];
#pragma unroll
        for (int d = 1; d < 64; d <<= 1) {
            float u = __shfl_up(L, d, 64);
            if (lane >= d) L += u;
        }
        float Ltot = __shfl(L, 63, 64);
        ws[t] = expf(Ltot - L) * dt[(m0tok + t)*NHEADS + hd];
        if (t == 63) Pbuf[bid] = expf(Ltot);
    }
    __syncthreads();
#pragma unroll 4
    for (int i = 0; i < 32; i++) {
        int idx = i*256 + t;
        int tt = idx >> 7, p = idx & 127;
        const bf16_t* row = xBCb + (size_t)(m0tok + tt)*CONVDIM;
        float xv = bf2f(*(const short*)&row[hd*HEADDIM + p]);
        XT[p*LDT + tt] = __float2bfloat16(xv * ws[tt]);
        BT[p*LDT + tt] = row[DINNER + p];
    }
    __syncthreads();
    int m0w = wave * 32;
    f32x4 acc[2][8];
#pragma unroll
    for (int mi = 0; mi < 2; mi++)
#pragma unroll
        for (int ni = 0; ni < 8; ni++) acc[mi][ni] = (f32x4){0.f,0.f,0.f,0.f};
#pragma unroll
    for (int k0 = 0; k0 < 64; k0 += 32) {
        short8 a[2];
#pragma unroll
        for (int mi = 0; mi < 2; mi++)
            a[mi] = *(const short8*)&XT[(m0w + mi*16 + lr)*LDT + k0 + quad*8];
#pragma unroll
        for (int ni = 0; ni < 8; ni++) {
            short8 bb = *(const short8*)&BT[(ni*16 + lr)*LDT + k0 + quad*8];
#pragma unroll
            for (int mi = 0; mi < 2; mi++)
                acc[mi][ni] = __builtin_amdgcn_mfma_f32_16x16x32_bf16(a[mi], bb, acc[mi][ni], 0, 0, 0);
        }
    }
    bf16_t* outp = Sloc + (size_t)bid * 16384;
#pragma unroll
    for (int mi = 0; mi < 2; mi++)
#pragma unroll
        for (int ni = 0; ni < 8; ni++)
#pragma unroll
            for (int r = 0; r < 4; r++) {
                int p = m0w + mi*16 + quad*4 + r;
                int n = ni*16 + lr;
                outp[p*128 + n] = __float2bfloat16(acc[mi][ni][r]);
            }
}

// ---------------- scan phase B: inter-chunk recurrence, out-of-place, 512-way ----------------
__global__ __launch_bounds__(256) void scanB(const bf16_t* __restrict__ Sloc,
                                             bf16_t* __restrict__ Sini,
                                             const float* __restrict__ Pbuf) {
    int bid = blockIdx.x;                   // 512 = 16 bh * 32 slices
    int bh = bid >> 5, slice = bid & 31;
    int t = threadIdx.x;
    int off = slice*512 + t*2;
    size_t base = (size_t)bh * NCHUNK * 16384;
    float run0 = 0.f, run1 = 0.f;
    for (int cc = 0; cc < NCHUNK; cc++) {
        unsigned raw = *(const unsigned*)(Sloc + base + (size_t)cc*16384 + off);
        float P = Pbuf[bh*NCHUNK + cc];
        unsigned o0 = (unsigned)(unsigned short)f2bf_s(run0);
        unsigned o1 = (unsigned)(unsigned short)f2bf_s(run1);
        *(unsigned*)(Sini + base + (size_t)cc*16384 + off) = o0 | (o1 << 16);
        run0 = run0*P + bf2f((short)(raw & 0xffff));
        run1 = run1*P + bf2f((short)(raw >> 16));
    }
}

// ---------------- scan phase C (MFMA): Y = diag(e^{L_t}) C @ S_init^T + M @ X + D*x ----------------
__global__ __launch_bounds__(256) void scanC_mfma(const bf16_t* __restrict__ xBCb,
                                                  const float* __restrict__ dt,
                                                  const float* __restrict__ ldA,
                                                  const bf16_t* __restrict__ Sini,
                                                  const float* __restrict__ Dskip,
                                                  float* __restrict__ ybuf) {
    int bid = blockIdx.x;
    int c = bid & 31, hd = (bid >> 5) & 7, b = bid >> 8;
    int t = threadIdx.x, wave = t >> 6, lane = t & 63;
    int lr = lane & 15, quad = lane >> 4;
    __shared__ bf16_t XT[128*LDT];   // [p][t]
    __shared__ bf16_t Mlds[64*LDT];  // [t][s]
    __shared__ float Ls[CHUNK], dts[CHUNK];
    int m0tok = b*SEQ + c*CHUNK;
    if (t < 64) {
        float L = ldA[(m0tok + t)*NHEADS + hd];
#pragma unroll
        for (int d = 1; d < 64; d <<= 1) {
            float u = __shfl_up(L, d, 64);
            if (lane >= d) L += u;
        }
        Ls[t] = L;
        dts[t] = dt[(m0tok + t)*NHEADS + hd];
    }
#pragma unroll 4
    for (int i = 0; i < 32; i++) {
        int idx = i*256 + t;
        int tt = idx >> 7, p = idx & 127;
        XT[p*LDT + tt] = xBCb[(size_t)(m0tok + tt)*CONVDIM + hd*HEADDIM + p];
    }
    __syncthreads();
    const bf16_t* Crow = xBCb + (size_t)m0tok*CONVDIM + DINNER + DSTATE;
    const bf16_t* Brow = xBCb + (size_t)m0tok*CONVDIM + DINNER;
    // --- G = C @ B^T for t-rows [wave*16, wave*16+16) ---
    f32x4 g[4];
#pragma unroll
    for (int si = 0; si < 4; si++) g[si] = (f32x4){0.f,0.f,0.f,0.f};
#pragma unroll
    for (int k0 = 0; k0 < 128; k0 += 32) {
        short8 a = *(const short8*)(Crow + (size_t)(wave*16 + lr)*CONVDIM + k0 + quad*8);
#pragma unroll
        for (int si = 0; si < 4; si++) {
            short8 bb = *(const short8*)(Brow + (size_t)(si*16 + lr)*CONVDIM + k0 + quad*8);
            g[si] = __builtin_amdgcn_mfma_f32_16x16x32_bf16(a, bb, g[si], 0, 0, 0);
        }
    }
#pragma unroll
    for (int si = 0; si < 4; si++)
#pragma unroll
        for (int r = 0; r < 4; r++) {
            int tt = wave*16 + quad*4 + r;
            int ss = si*16 + lr;
            float v = (ss <= tt) ? g[si][r] * expf(Ls[tt] - Ls[ss]) * dts[ss] : 0.f;
            Mlds[tt*LDT + ss] = __float2bfloat16(v);
        }
    __syncthreads();
    // --- Y: wave handles p-cols [wave*32, wave*32+32) ---
    int p0 = wave * 32;
    f32x4 acc[4][2];
#pragma unroll
    for (int mi = 0; mi < 4; mi++)
#pragma unroll
        for (int ni = 0; ni < 2; ni++) acc[mi][ni] = (f32x4){0.f,0.f,0.f,0.f};
    // Y_inter = C @ S_init^T  (K = n = 128)
    const bf16_t* Sb = Sini + (size_t)bid * 16384;
#pragma unroll
    for (int k0 = 0; k0 < 128; k0 += 32) {
        short8 aC[4];
#pragma unroll
        for (int mi = 0; mi < 4; mi++)
            aC[mi] = *(const short8*)(Crow + (size_t)(mi*16 + lr)*CONVDIM + k0 + quad*8);
#pragma unroll
        for (int ni = 0; ni < 2; ni++) {
            short8 bb = *(const short8*)(Sb + (size_t)(p0 + ni*16 + lr)*128 + k0 + quad*8);
#pragma unroll
            for (int mi = 0; mi < 4; mi++)
                acc[mi][ni] = __builtin_amdgcn_mfma_f32_16x16x32_bf16(aC[mi], bb, acc[mi][ni], 0, 0, 0);
        }
    }
    // scale rows by exp(L_t)
#pragma unroll
    for (int mi = 0; mi < 4; mi++) {
        float el[4];
#pragma unroll
        for (int r = 0; r < 4; r++) el[r] = expf(Ls[mi*16 + quad*4 + r]);
#pragma unroll
        for (int ni = 0; ni < 2; ni++)
#pragma unroll
            for (int r = 0; r < 4; r++) acc[mi][ni][r] *= el[r];
    }
    // Y_intra = M @ X  (K = s = 64)
#pragma unroll
    for (int k0 = 0; k0 < 64; k0 += 32) {
        short8 aM[4];
#pragma unroll
        for (int mi = 0; mi < 4; mi++)
            aM[mi] = *(const short8*)&Mlds[(mi*16 + lr)*LDT + k0 + quad*8];
#pragma unroll
        for (int ni = 0; ni < 2; ni++) {
            short8 bb = *(const short8*)&XT[(p0 + ni*16 + lr)*LDT + k0 + quad*8];
#pragma unroll
            for (int mi = 0; mi < 4; mi++)
                acc[mi][ni] = __builtin_amdgcn_mfma_f32_16x16x32_bf16(aM[mi], bb, acc[mi][ni], 0, 0, 0);
        }
    }
    float dsk = Dskip[hd];
#pragma unroll
    for (int mi = 0; mi < 4; mi++)
#pragma unroll
        for (int ni = 0; ni < 2; ni++)
#pragma unroll
            for (int r = 0; r < 4; r++) {
                int tt = mi*16 + quad*4 + r;
                int pp = p0 + ni*16 + lr;
                float xv = bf2f(*(const short*)&XT[pp*LDT + tt]);
                int m = m0tok + tt;
                ybuf[(size_t)m*DINNER + hd*HEADDIM + pp] = acc[mi][ni][r] + dsk*xv;
            }
}

// ---------------- fused gate(silu(z)) + RMSNorm + out_proj (16 tokens/block) ----------------
__global__ __launch_bounds__(256) void gate_out(const float* __restrict__ ybuf,
                                                const bf16_t* __restrict__ zxb,
                                                const float* __restrict__ gw,
                                                const bf16_t* __restrict__ Wb,
                                                float* __restrict__ mix) {
    int blk = blockIdx.x, t = threadIdx.x;
    int tok0 = blk * 16;
    int tt = t >> 4, cg = t & 15;
    int ch0 = cg * 64;
    __shared__ bf16_t A[16*1032];
    float vals[64];
    const float*  yr = ybuf + (size_t)(tok0 + tt)*DINNER + ch0;
    const bf16_t* zr = zxb  + (size_t)(tok0 + tt)*NPROJ  + ch0;
    float ss = 0.f;
#pragma unroll
    for (int i = 0; i < 64; i += 4) {
        f32x4 y = *(const f32x4*)(yr + i);
        short4v z = *(const short4v*)(zr + i);
#pragma unroll
        for (int r = 0; r < 4; r++) {
            float v = y[r] * silu_f(bf2f(z[r]));
            vals[i + r] = v; ss += v*v;
        }
    }
#pragma unroll
    for (int d = 1; d < 16; d <<= 1) ss += __shfl_xor(ss, d, 64);
    float rstd = rsqrtf(ss*(1.f/1024.f) + 1e-5f);
#pragma unroll
    for (int i = 0; i < 64; i += 4) {
        short4v pk;
#pragma unroll
        for (int r = 0; r < 4; r++) pk[r] = f2bf_s(vals[i+r]*rstd*gw[ch0+i+r]);
        *(short4v*)&A[tt*1032 + ch0 + i] = pk;
    }
    __syncthreads();
    int wave = t >> 6, lane = t & 63, lr = lane & 15, quad = lane >> 4;
    f32x4 acc[2];
    acc[0] = (f32x4){0.f,0.f,0.f,0.f}; acc[1] = (f32x4){0.f,0.f,0.f,0.f};
    for (int k0 = 0; k0 < 1024; k0 += 32) {
        short8 a = *(const short8*)&A[lr*1032 + k0 + quad*8];
#pragma unroll
        for (int j = 0; j < 2; j++) {
            int col = wave*32 + j*16 + lr;
            short8 bb = *(const short8*)(Wb + (size_t)col*DINNER + k0 + quad*8);
            acc[j] = __builtin_amdgcn_mfma_f32_16x16x32_bf16(a, bb, acc[j], 0, 0, 0);
        }
    }
#pragma unroll
    for (int j = 0; j < 2; j++)
#pragma unroll
        for (int r = 0; r < 4; r++) {
            int row = tok0 + quad*4 + r;
            int col = wave*32 + j*16 + lr;
            mix[(size_t)row*DMODEL + col] = acc[j][r];
        }
}

// ---------------- fused residual + LN2 + MLP (16 tokens/block) ----------------
__global__ __launch_bounds__(256) void ln_mlp(const float* __restrict__ mix,
                                              const float* __restrict__ resid,
                                              const float* __restrict__ w,
                                              const float* __restrict__ b,
                                              const bf16_t* __restrict__ Wm,
                                              const float* __restrict__ mb,
                                              float* __restrict__ out) {
    int blk = blockIdx.x, t = threadIdx.x;
    int tok0 = blk * 16;
    int tt = t >> 4, cg = t & 15;
    int ch0 = cg * 8;
    __shared__ bf16_t A[16*136];
    const float* xr = mix   + (size_t)(tok0 + tt)*DMODEL + ch0;
    const float* rr = resid + (size_t)(tok0 + tt)*DMODEL + ch0;
    float v[8];
    {
        f32x4 x0 = *(const f32x4*)xr, x1 = *(const f32x4*)(xr + 4);
        f32x4 r0 = *(const f32x4*)rr, r1 = *(const f32x4*)(rr + 4);
#pragma unroll
        for (int r = 0; r < 4; r++) { v[r] = x0[r] + r0[r]; v[4+r] = x1[r] + r1[r]; }
    }
    float s = 0.f, sq = 0.f;
#pragma unroll
    for (int i = 0; i < 8; i++) { s += v[i]; sq += v[i]*v[i]; }
#pragma unroll
    for (int d = 1; d < 16; d <<= 1) { s += __shfl_xor(s, d, 64); sq += __shfl_xor(sq, d, 64); }
    float mean = s * (1.f/128.f);
    float var  = sq * (1.f/128.f) - mean*mean;
    float rstd = rsqrtf(var + 1e-5f);
    {
        short4v p0, p1;
#pragma unroll
        for (int r = 0; r < 4; r++) {
            p0[r] = f2bf_s((v[r]   - mean)*rstd*w[ch0+r]   + b[ch0+r]);
            p1[r] = f2bf_s((v[4+r] - mean)*rstd*w[ch0+4+r] + b[ch0+4+r]);
        }
        *(short4v*)&A[tt*136 + ch0]     = p0;
        *(short4v*)&A[tt*136 + ch0 + 4] = p1;
    }
    __syncthreads();
    int wave = t >> 6, lane = t & 63, lr = lane & 15, quad = lane >> 4;
    f32x4 acc[2];
    acc[0] = (f32x4){0.f,0.f,0.f,0.f}; acc[1] = (f32x4){0.f,0.f,0.f,0.f};
#pragma unroll
    for (int k0 = 0; k0 < 128; k0 += 32) {
        short8 a = *(const short8*)&A[lr*136 + k0 + quad*8];
#pragma unroll
        for (int j = 0; j < 2; j++) {
            int col = wave*32 + j*16 + lr;
            short8 bb = *(const short8*)(Wm + (size_t)col*DMODEL + k0 + quad*8);
            acc[j] = __builtin_amdgcn_mfma_f32_16x16x32_bf16(a, bb, acc[j], 0, 0, 0);
        }
    }
#pragma unroll
    for (int j = 0; j < 2; j++)
#pragma unroll
        for (int r = 0; r < 4; r++) {
            int row = tok0 + quad*4 + r;
            int col = wave*32 + j*16 + lr;
            out[(size_t)row*DMODEL + col] = acc[j][r] + mb[col];
        }
}

extern "C" void kernel_launch(void* const* d_in, const int* in_sizes, int n_in,
                              void* d_out, int out_size, void* d_ws, size_t ws_size,
                              hipStream_t stream) {
    const float* hidden  = (const float*)d_in[0];
    const float* w_in    = (const float*)d_in[1];
    const float* conv_w  = (const float*)d_in[2];
    const float* conv_b  = (const float*)d_in[3];
    const float* dt_bias = (const float*)d_in[4];
    const float* A_log   = (const float*)d_in[5];
    const float* D_skip  = (const float*)d_in[6];
    const float* gnorm_w = (const float*)d_in[7];
    const float* w_out   = (const float*)d_in[8];
    const float* ln1_w   = (const float*)d_in[9];
    const float* ln1_b   = (const float*)d_in[10];
    const float* ln2_w   = (const float*)d_in[11];
    const float* ln2_b   = (const float*)d_in[12];
    const float* mlp_w   = (const float*)d_in[13];
    const float* mlp_b   = (const float*)d_in[14];
    float* out = (float*)d_out;

    char* ws = (char*)d_ws;
    size_t off = 0;
    auto alloc = [&](size_t bytes) -> void* {
        void* p = ws + off;
        off = (off + bytes + 255) & ~(size_t)255;
        return p;
    };
    bf16_t* h_bf   = (bf16_t*)alloc((size_t)NTOK*DMODEL*2);
    bf16_t* w_in_bf= (bf16_t*)alloc((size_t)NPROJ*DMODEL*2);
    bf16_t* w_out_bf=(bf16_t*)alloc((size_t)DMODEL*DINNER*2);
    bf16_t* mlp_bf = (bf16_t*)alloc((size_t)DMODEL*DMODEL*2);
    bf16_t* zx_bf  = (bf16_t*)alloc((size_t)NTOK*NPROJ*2);
    bf16_t* xBCb   = (bf16_t*)alloc((size_t)NTOK*CONVDIM*2);
    float*  dtb    = (float*) alloc((size_t)NTOK*NHEADS*4);
    float*  ldAb   = (float*) alloc((size_t)NTOK*NHEADS*4);
    bf16_t* Sloc   = (bf16_t*)alloc((size_t)B_SZ*NHEADS*NCHUNK*16384*2);
    bf16_t* Sini   = (bf16_t*)alloc((size_t)B_SZ*NHEADS*NCHUNK*16384*2);
    float*  Pbuf   = (float*) alloc((size_t)B_SZ*NHEADS*NCHUNK*4);
    float*  ybuf   = (float*) alloc((size_t)NTOK*DINNER*4);
    float*  mix    = (float*) alloc((size_t)NTOK*DMODEL*4);
    (void)ws_size; (void)in_sizes; (void)n_in; (void)out_size;

    // fused: weight casts + LN1 + dt head
    {
        int na = NPROJ*DMODEL, nb = DMODEL*DINNER, nc = DMODEL*DMODEL;
        int castBlocks = (na + nb + nc + 127) / 128;
        head_fused<<<NTOK + castBlocks, 128, 0, stream>>>(
            hidden, ln1_w, ln1_b, w_in, dt_bias, A_log, h_bf, dtb, ldAb,
            w_in, na, w_out, nb, mlp_w, nc, w_in_bf, w_out_bf, mlp_bf);
    }
    // in_proj (z + xBC columns), bf16 out
    gemm_bf<<<dim3(NTOK/64, NPROJ/64), 256, 0, stream>>>(h_bf, w_in_bf, zx_bf,
                                                         NTOK, NPROJ, DMODEL);
    // conv + silu (bf16, x4 vectorized, channel-coalesced)
    conv_silu<<<((size_t)NTOK*CONVDIM/4 + 255)/256, 256, 0, stream>>>(zx_bf, conv_w, conv_b, xBCb);
    // chunked scan (SSD, MFMA); SSA dataflow Sloc -> Sini
    scanA_mfma<<<B_SZ*NHEADS*NCHUNK, 256, 0, stream>>>(xBCb, dtb, ldAb, Sloc, Pbuf);
    scanB<<<B_SZ*NHEADS*NCHUNK, 256, 0, stream>>>(Sloc, Sini, Pbuf);
    scanC_mfma<<<B_SZ*NHEADS*NCHUNK, 256, 0, stream>>>(xBCb, dtb, ldAb, Sini, D_skip, ybuf);
    // fused gate + RMSNorm + out_proj
    gate_out<<<NTOK/16, 256, 0, stream>>>(ybuf, zx_bf, gnorm_w, w_out_bf, mix);
    // fused residual + LN2 + MLP
    ln_mlp<<<NTOK/16, 256, 0, stream>>>(mix, hidden, ln2_w, ln2_b, mlp_bf, mlp_b, out);
}